// Round 1
// baseline (527.920 us; speedup 1.0000x reference)
//
#include <hip/hip_runtime.h>

// Problem constants: B=4, S=2048 -> T=8192 tokens; H=512, F=2048, E=8, K=2.
#define T_TOKENS 8192
#define HD 512
#define FD 2048
#define NE 8
#define CAP 8192   // per-expert bucket capacity (worst case all tokens -> one expert)

#define BM 128
#define BN 128
#define BK 32
#define LDA 40     // padded LDS row stride (bf16 elems): 80B -> 20-bank step, 2-way max (free)

typedef __attribute__((ext_vector_type(8))) short short8;   // 8 bf16 = 4 VGPRs
typedef __attribute__((ext_vector_type(4))) float f32x4;    // MFMA accumulator

__device__ __forceinline__ ushort f2bf(float f) {
  union { float f; unsigned u; } v; v.f = f;
  unsigned u = v.u;
  return (ushort)((u + 0x7fffu + ((u >> 16) & 1u)) >> 16);  // RNE
}

// ---------------- fp32 -> bf16 bulk convert ----------------
__global__ void cvt_bf16(const float4* __restrict__ src, ushort4* __restrict__ dst, int n4) {
  int i = blockIdx.x * blockDim.x + threadIdx.x;
  int st = gridDim.x * blockDim.x;
  for (; i < n4; i += st) {
    float4 v = src[i];
    ushort4 o;
    o.x = f2bf(v.x); o.y = f2bf(v.y); o.z = f2bf(v.z); o.w = f2bf(v.w);
    dst[i] = o;
  }
}

// ---------------- router: logits -> softmax -> top2 -> buckets ----------------
// One wave (64 lanes) per token. Full fp32 to stay bit-close to the reference
// (an index flip at the top-2 boundary would blow the absmax threshold).
__global__ void router_kernel(const float* __restrict__ x, const float* __restrict__ rw,
                              float* __restrict__ probs_out, float* __restrict__ topk_out,
                              int* __restrict__ counts, int* __restrict__ bucket_tok,
                              float* __restrict__ bucket_w, int4* __restrict__ tok_info) {
  int wave = threadIdx.x >> 6, lane = threadIdx.x & 63;
  int t = blockIdx.x * 4 + wave;
  float acc[NE];
#pragma unroll
  for (int e = 0; e < NE; e++) acc[e] = 0.f;
  const float* xr = x + (size_t)t * HD;
  for (int c = 0; c < HD; c += 64) {
    float xv = xr[c + lane];
#pragma unroll
    for (int e = 0; e < NE; e++) acc[e] += xv * rw[e * HD + c + lane];
  }
#pragma unroll
  for (int e = 0; e < NE; e++) {
#pragma unroll
    for (int s = 32; s > 0; s >>= 1) acc[e] += __shfl_xor(acc[e], s, 64);
  }
  if (lane == 0) {
    float m = acc[0];
#pragma unroll
    for (int e = 1; e < NE; e++) m = fmaxf(m, acc[e]);
    float p[NE], s = 0.f;
#pragma unroll
    for (int e = 0; e < NE; e++) { p[e] = expf(acc[e] - m); s += p[e]; }
    float inv = 1.f / s;
#pragma unroll
    for (int e = 0; e < NE; e++) { p[e] *= inv; probs_out[(size_t)t * NE + e] = p[e]; }
    // top-2, ties -> lowest index (matches jax.lax.top_k)
    int i0 = 0;
#pragma unroll
    for (int e = 1; e < NE; e++) if (p[e] > p[i0]) i0 = e;
    int i1 = (i0 == 0) ? 1 : 0;
#pragma unroll
    for (int e = 0; e < NE; e++) if (e != i0 && p[e] > p[i1]) i1 = e;
    float r = 1.f / (p[i0] + p[i1] + 1e-9f);
    float w0 = p[i0] * r, w1 = p[i1] * r;
    topk_out[(size_t)t * 2 + 0] = (float)i0;
    topk_out[(size_t)t * 2 + 1] = (float)i1;
    int s0 = atomicAdd(&counts[i0], 1);
    bucket_tok[i0 * CAP + s0] = t; bucket_w[i0 * CAP + s0] = w0;
    int s1 = atomicAdd(&counts[i1], 1);
    bucket_tok[i1 * CAP + s1] = t; bucket_w[i1 * CAP + s1] = w1;
    tok_info[t] = make_int4(i0, i1, s0, s1);
  }
}

__global__ void scan_kernel(const int* __restrict__ counts, int* __restrict__ offsets) {
  if (threadIdx.x == 0) {
    int o = 0;
#pragma unroll
    for (int e = 0; e < NE; e++) { offsets[e] = o; o += counts[e]; }
  }
}

// ---------------- grouped GEMM (bf16 MFMA 16x16x32), FC1 and FC2 ----------------
// C[m, n] = sum_k A[m,k] * Bt[n,k]   (both operands row-major with K contiguous)
// FC1: A rows gathered from xb via bucket_tok; epilogue = +bias, exact GELU, bf16 store.
// FC2: A rows = compact intermediate; epilogue = gate_w * (acc + bias), fp32 store.
template <bool IS_FC1>
__global__ __launch_bounds__(256, 2)
void ffn_gemm(const ushort* __restrict__ Ab, const ushort* __restrict__ Bw,
              const float* __restrict__ bias, const int* __restrict__ counts,
              const int* __restrict__ offsets, const int* __restrict__ bucket_tok,
              const float* __restrict__ bucket_w, ushort* __restrict__ Aout,
              float* __restrict__ Yout, int KD, int ND) {
  int e = blockIdx.z;
  int cnt = counts[e];
  int m0 = blockIdx.y * BM;
  if (m0 >= cnt) return;
  int n0 = blockIdx.x * BN;
  int off = offsets[e];

  __shared__ alignas(16) ushort As[BM * LDA];
  __shared__ alignas(16) ushort Bs[BN * LDA];

  int tid = threadIdx.x;
  int wid = tid >> 6, lid = tid & 63;
  int wm = wid >> 1, wn = wid & 1;
  int q = lid >> 4, l16 = lid & 15;

  // staging: 128 rows x 32 bf16 per tile; thread covers 2 chunks of 8 bf16 (16B)
  int crow = tid >> 2;              // rows 0..63  (second chunk: +64)
  int cseg = (tid & 3) * 8;         // elem offset within the 32-elem k-slab

  int mr0 = min(m0 + crow, cnt - 1);
  int mr1 = min(m0 + crow + 64, cnt - 1);
  const ushort *a0, *a1;
  if (IS_FC1) {
    a0 = Ab + (size_t)bucket_tok[e * CAP + mr0] * KD + cseg;
    a1 = Ab + (size_t)bucket_tok[e * CAP + mr1] * KD + cseg;
  } else {
    a0 = Ab + (size_t)(off + mr0) * KD + cseg;
    a1 = Ab + (size_t)(off + mr1) * KD + cseg;
  }
  const ushort* b0 = Bw + ((size_t)e * ND + n0 + crow) * KD + cseg;
  const ushort* b1 = b0 + (size_t)64 * KD;
  unsigned lw0 = crow * LDA + cseg;
  unsigned lw1 = (crow + 64) * LDA + cseg;

  f32x4 acc[4][4] = {};

  for (int k0 = 0; k0 < KD; k0 += BK) {
    *(uint4*)&As[lw0] = *(const uint4*)(a0 + k0);
    *(uint4*)&As[lw1] = *(const uint4*)(a1 + k0);
    *(uint4*)&Bs[lw0] = *(const uint4*)(b0 + k0);
    *(uint4*)&Bs[lw1] = *(const uint4*)(b1 + k0);
    __syncthreads();
    short8 af[4], bf[4];
#pragma unroll
    for (int i = 0; i < 4; i++)
      af[i] = *(const short8*)&As[(wm * 64 + i * 16 + l16) * LDA + q * 8];
#pragma unroll
    for (int j = 0; j < 4; j++)
      bf[j] = *(const short8*)&Bs[(wn * 64 + j * 16 + l16) * LDA + q * 8];
#pragma unroll
    for (int i = 0; i < 4; i++)
#pragma unroll
      for (int j = 0; j < 4; j++)
        acc[i][j] = __builtin_amdgcn_mfma_f32_16x16x32_bf16(af[i], bf[j], acc[i][j], 0, 0, 0);
    __syncthreads();
  }

  // epilogue: C/D layout col=lane&15, row=(lane>>4)*4+reg
#pragma unroll
  for (int j = 0; j < 4; j++) {
    int ncol = n0 + wn * 64 + j * 16 + l16;
    float bcol = bias[(size_t)e * ND + ncol];
#pragma unroll
    for (int i = 0; i < 4; i++) {
#pragma unroll
      for (int r = 0; r < 4; r++) {
        int m = m0 + wm * 64 + i * 16 + q * 4 + r;
        if (m < cnt) {
          float v = acc[i][j][r] + bcol;
          if (IS_FC1) {
            float g = 0.5f * v * (1.0f + erff(v * 0.70710678118654752f));
            Aout[(size_t)(off + m) * ND + ncol] = f2bf(g);
          } else {
            float wgt = bucket_w[e * CAP + m];
            Yout[(size_t)(off + m) * ND + ncol] = wgt * v;
          }
        }
      }
    }
  }
}

// ---------------- combine: out[t] = Y[row(e0,s0)] + Y[row(e1,s1)] ----------------
__global__ void combine_kernel(const float4* __restrict__ Y, const int4* __restrict__ tok_info,
                               const int* __restrict__ offsets, float4* __restrict__ out) {
  int t = blockIdx.x;
  int4 ti = tok_info[t];
  int g0 = offsets[ti.x] + ti.z;
  int g1 = offsets[ti.y] + ti.w;
  int i = threadIdx.x;  // 128 threads, H/4 = 128 float4 per row
  float4 a = Y[(size_t)g0 * (HD / 4) + i];
  float4 b = Y[(size_t)g1 * (HD / 4) + i];
  out[(size_t)t * (HD / 4) + i] = make_float4(a.x + b.x, a.y + b.y, a.z + b.z, a.w + b.w);
}

extern "C" void kernel_launch(void* const* d_in, const int* in_sizes, int n_in,
                              void* d_out, int out_size, void* d_ws, size_t ws_size,
                              hipStream_t stream) {
  const float* x    = (const float*)d_in[0];
  const float* rw   = (const float*)d_in[1];
  const float* fc1w = (const float*)d_in[2];
  const float* fc1b = (const float*)d_in[3];
  const float* fc2w = (const float*)d_in[4];
  const float* fc2b = (const float*)d_in[5];

  float* out   = (float*)d_out;
  float* probs = out + (size_t)T_TOKENS * HD;
  float* topk  = probs + (size_t)T_TOKENS * NE;

  char* p = (char*)d_ws;
  auto carve = [&](size_t bytes) { char* r = p; p += (bytes + 255) & ~(size_t)255; return r; };
  int*    counts     = (int*)carve(NE * sizeof(int));
  int*    offsets    = (int*)carve(NE * sizeof(int));
  int*    bucket_tok = (int*)carve((size_t)NE * CAP * sizeof(int));
  float*  bucket_w   = (float*)carve((size_t)NE * CAP * sizeof(float));
  int4*   tok_info   = (int4*)carve((size_t)T_TOKENS * sizeof(int4));
  ushort* xb   = (ushort*)carve((size_t)T_TOKENS * HD * 2);
  ushort* w1b  = (ushort*)carve((size_t)NE * FD * HD * 2);
  ushort* w2b  = (ushort*)carve((size_t)NE * HD * FD * 2);
  ushort* Abuf = (ushort*)carve((size_t)T_TOKENS * 2 * FD * 2);  // compact GELU out, bf16
  float*  Y    = (float*)carve((size_t)T_TOKENS * 2 * HD * 4);   // gated FC2 rows, fp32

  hipMemsetAsync(counts, 0, NE * sizeof(int), stream);
  cvt_bf16<<<2048, 256, 0, stream>>>((const float4*)x, (ushort4*)xb, T_TOKENS * HD / 4);
  cvt_bf16<<<2048, 256, 0, stream>>>((const float4*)fc1w, (ushort4*)w1b, NE * FD * HD / 4);
  cvt_bf16<<<2048, 256, 0, stream>>>((const float4*)fc2w, (ushort4*)w2b, NE * HD * FD / 4);
  router_kernel<<<T_TOKENS / 4, 256, 0, stream>>>(x, rw, probs, topk, counts, bucket_tok,
                                                  bucket_w, tok_info);
  scan_kernel<<<1, 64, 0, stream>>>(counts, offsets);
  ffn_gemm<true><<<dim3(FD / BN, CAP / BM, NE), 256, 0, stream>>>(
      xb, w1b, fc1b, counts, offsets, bucket_tok, bucket_w, Abuf, nullptr, HD, FD);
  ffn_gemm<false><<<dim3(HD / BN, CAP / BM, NE), 256, 0, stream>>>(
      Abuf, w2b, fc2b, counts, offsets, bucket_tok, bucket_w, nullptr, Y, FD, HD);
  combine_kernel<<<T_TOKENS, 128, 0, stream>>>((const float4*)Y, tok_info, offsets, (float4*)out);
}

// Round 2
// 376.607 us; speedup vs baseline: 1.4018x; 1.4018x over previous
//
#include <hip/hip_runtime.h>

// Problem constants: B=4, S=2048 -> T=8192 tokens; H=512, F=2048, E=8, K=2.
#define T_TOKENS 8192
#define HD 512
#define FD 2048
#define NE 8
#define CAP 8192   // per-expert bucket capacity (worst case all tokens -> one expert)
#define CSTRIDE 32 // counter padding: 32 ints = 128B, one counter per cache line

#define BM 128
#define BN 128
#define BK 32
#define LDA 40     // padded LDS row stride (bf16 elems): 80B -> 20-bank step, 2-way max (free)

typedef __attribute__((ext_vector_type(8))) short short8;   // 8 bf16 = 4 VGPRs
typedef __attribute__((ext_vector_type(4))) float f32x4;    // MFMA accumulator

__device__ __forceinline__ ushort f2bf(float f) {
  union { float f; unsigned u; } v; v.f = f;
  unsigned u = v.u;
  return (ushort)((u + 0x7fffu + ((u >> 16) & 1u)) >> 16);  // RNE
}

// ---------------- fp32 -> bf16 bulk convert ----------------
__global__ void cvt_bf16(const float4* __restrict__ src, ushort4* __restrict__ dst, int n4) {
  int i = blockIdx.x * blockDim.x + threadIdx.x;
  int st = gridDim.x * blockDim.x;
  for (; i < n4; i += st) {
    float4 v = src[i];
    ushort4 o;
    o.x = f2bf(v.x); o.y = f2bf(v.y); o.z = f2bf(v.z); o.w = f2bf(v.w);
    dst[i] = o;
  }
}

// ---------------- router: logits -> softmax -> top2 -> buckets ----------------
// One wave computes 16 tokens sequentially (64 tokens per 256-thread block).
// Slot assignment is hierarchical: LDS atomics for local slots, then 8 global
// atomics per block (padded to separate cache lines) for the block's base.
// R1 post-mortem: flat per-token atomics on 8 counters in ONE cache line
// serialized at L2 -> 193 us with 3.7% VALUBusy. This removes 94% of the
// same-line RMW traffic.
#define TPW 16
__global__ void router_kernel(const float* __restrict__ x, const float* __restrict__ rw,
                              float* __restrict__ probs_out, float* __restrict__ topk_out,
                              int* __restrict__ counts, int* __restrict__ bucket_tok,
                              float* __restrict__ bucket_w, int4* __restrict__ tok_info) {
  __shared__ int lcnt[NE];
  __shared__ int lbase[NE];
  __shared__ int ls_e0[64], ls_e1[64], ls_s0[64], ls_s1[64];
  __shared__ float ls_w0[64], ls_w1[64];

  int wave = threadIdx.x >> 6, lane = threadIdx.x & 63;
  if (threadIdx.x < NE) lcnt[threadIdx.x] = 0;
  __syncthreads();

  int tbase = blockIdx.x * 64;
  for (int it = 0; it < TPW; it++) {
    int lt = wave * TPW + it;
    int t = tbase + lt;
    float acc[NE];
#pragma unroll
    for (int e = 0; e < NE; e++) acc[e] = 0.f;
    const float* xr = x + (size_t)t * HD;
    for (int c = 0; c < HD; c += 64) {
      float xv = xr[c + lane];
#pragma unroll
      for (int e = 0; e < NE; e++) acc[e] += xv * rw[e * HD + c + lane];
    }
#pragma unroll
    for (int e = 0; e < NE; e++) {
#pragma unroll
      for (int s = 32; s > 0; s >>= 1) acc[e] += __shfl_xor(acc[e], s, 64);
    }
    if (lane == 0) {
      float m = acc[0];
#pragma unroll
      for (int e = 1; e < NE; e++) m = fmaxf(m, acc[e]);
      float p[NE], s = 0.f;
#pragma unroll
      for (int e = 0; e < NE; e++) { p[e] = expf(acc[e] - m); s += p[e]; }
      float inv = 1.f / s;
#pragma unroll
      for (int e = 0; e < NE; e++) { p[e] *= inv; probs_out[(size_t)t * NE + e] = p[e]; }
      // top-2, ties -> lowest index (matches jax.lax.top_k)
      int i0 = 0;
#pragma unroll
      for (int e = 1; e < NE; e++) if (p[e] > p[i0]) i0 = e;
      int i1 = (i0 == 0) ? 1 : 0;
#pragma unroll
      for (int e = 0; e < NE; e++) if (e != i0 && p[e] > p[i1]) i1 = e;
      float r = 1.f / (p[i0] + p[i1] + 1e-9f);
      topk_out[(size_t)t * 2 + 0] = (float)i0;
      topk_out[(size_t)t * 2 + 1] = (float)i1;
      ls_e0[lt] = i0; ls_e1[lt] = i1;
      ls_w0[lt] = p[i0] * r; ls_w1[lt] = p[i1] * r;
      ls_s0[lt] = atomicAdd(&lcnt[i0], 1);
      ls_s1[lt] = atomicAdd(&lcnt[i1], 1);
    }
  }
  __syncthreads();
  if (threadIdx.x < NE)
    lbase[threadIdx.x] = atomicAdd(&counts[threadIdx.x * CSTRIDE], lcnt[threadIdx.x]);
  __syncthreads();
  if (threadIdx.x < 64) {
    int lt = threadIdx.x, t = tbase + lt;
    int e0 = ls_e0[lt], e1 = ls_e1[lt];
    int g0 = lbase[e0] + ls_s0[lt];
    int g1 = lbase[e1] + ls_s1[lt];
    bucket_tok[e0 * CAP + g0] = t; bucket_w[e0 * CAP + g0] = ls_w0[lt];
    bucket_tok[e1 * CAP + g1] = t; bucket_w[e1 * CAP + g1] = ls_w1[lt];
    tok_info[t] = make_int4(e0, e1, g0, g1);
  }
}

__global__ void scan_kernel(const int* __restrict__ counts, int* __restrict__ offsets) {
  if (threadIdx.x == 0) {
    int o = 0;
#pragma unroll
    for (int e = 0; e < NE; e++) { offsets[e] = o; o += counts[e * CSTRIDE]; }
  }
}

// ---------------- grouped GEMM (bf16 MFMA 16x16x32), FC1 and FC2 ----------------
// C[m, n] = sum_k A[m,k] * Bt[n,k]   (both operands row-major with K contiguous)
// FC1: A rows gathered from xb via bucket_tok; epilogue = +bias, exact GELU, bf16 store.
// FC2: A rows = compact intermediate; epilogue = gate_w * (acc + bias), fp32 store.
template <bool IS_FC1>
__global__ __launch_bounds__(256, 2)
void ffn_gemm(const ushort* __restrict__ Ab, const ushort* __restrict__ Bw,
              const float* __restrict__ bias, const int* __restrict__ counts,
              const int* __restrict__ offsets, const int* __restrict__ bucket_tok,
              const float* __restrict__ bucket_w, ushort* __restrict__ Aout,
              float* __restrict__ Yout, int KD, int ND) {
  int e = blockIdx.z;
  int cnt = counts[e * CSTRIDE];
  int m0 = blockIdx.y * BM;
  if (m0 >= cnt) return;
  int n0 = blockIdx.x * BN;
  int off = offsets[e];

  __shared__ alignas(16) ushort As[BM * LDA];
  __shared__ alignas(16) ushort Bs[BN * LDA];

  int tid = threadIdx.x;
  int wid = tid >> 6, lid = tid & 63;
  int wm = wid >> 1, wn = wid & 1;
  int q = lid >> 4, l16 = lid & 15;

  // staging: 128 rows x 32 bf16 per tile; thread covers 2 chunks of 8 bf16 (16B)
  int crow = tid >> 2;              // rows 0..63  (second chunk: +64)
  int cseg = (tid & 3) * 8;         // elem offset within the 32-elem k-slab

  int mr0 = min(m0 + crow, cnt - 1);
  int mr1 = min(m0 + crow + 64, cnt - 1);
  const ushort *a0, *a1;
  if (IS_FC1) {
    a0 = Ab + (size_t)bucket_tok[e * CAP + mr0] * KD + cseg;
    a1 = Ab + (size_t)bucket_tok[e * CAP + mr1] * KD + cseg;
  } else {
    a0 = Ab + (size_t)(off + mr0) * KD + cseg;
    a1 = Ab + (size_t)(off + mr1) * KD + cseg;
  }
  const ushort* b0 = Bw + ((size_t)e * ND + n0 + crow) * KD + cseg;
  const ushort* b1 = b0 + (size_t)64 * KD;
  unsigned lw0 = crow * LDA + cseg;
  unsigned lw1 = (crow + 64) * LDA + cseg;

  f32x4 acc[4][4] = {};

  for (int k0 = 0; k0 < KD; k0 += BK) {
    *(uint4*)&As[lw0] = *(const uint4*)(a0 + k0);
    *(uint4*)&As[lw1] = *(const uint4*)(a1 + k0);
    *(uint4*)&Bs[lw0] = *(const uint4*)(b0 + k0);
    *(uint4*)&Bs[lw1] = *(const uint4*)(b1 + k0);
    __syncthreads();
    short8 af[4], bf[4];
#pragma unroll
    for (int i = 0; i < 4; i++)
      af[i] = *(const short8*)&As[(wm * 64 + i * 16 + l16) * LDA + q * 8];
#pragma unroll
    for (int j = 0; j < 4; j++)
      bf[j] = *(const short8*)&Bs[(wn * 64 + j * 16 + l16) * LDA + q * 8];
#pragma unroll
    for (int i = 0; i < 4; i++)
#pragma unroll
      for (int j = 0; j < 4; j++)
        acc[i][j] = __builtin_amdgcn_mfma_f32_16x16x32_bf16(af[i], bf[j], acc[i][j], 0, 0, 0);
    __syncthreads();
  }

  // epilogue: C/D layout col=lane&15, row=(lane>>4)*4+reg
#pragma unroll
  for (int j = 0; j < 4; j++) {
    int ncol = n0 + wn * 64 + j * 16 + l16;
    float bcol = bias[(size_t)e * ND + ncol];
#pragma unroll
    for (int i = 0; i < 4; i++) {
#pragma unroll
      for (int r = 0; r < 4; r++) {
        int m = m0 + wm * 64 + i * 16 + q * 4 + r;
        if (m < cnt) {
          float v = acc[i][j][r] + bcol;
          if (IS_FC1) {
            float g = 0.5f * v * (1.0f + erff(v * 0.70710678118654752f));
            Aout[(size_t)(off + m) * ND + ncol] = f2bf(g);
          } else {
            float wgt = bucket_w[e * CAP + m];
            Yout[(size_t)(off + m) * ND + ncol] = wgt * v;
          }
        }
      }
    }
  }
}

// ---------------- combine: out[t] = Y[row(e0,s0)] + Y[row(e1,s1)] ----------------
__global__ void combine_kernel(const float4* __restrict__ Y, const int4* __restrict__ tok_info,
                               const int* __restrict__ offsets, float4* __restrict__ out) {
  int t = blockIdx.x;
  int4 ti = tok_info[t];
  int g0 = offsets[ti.x] + ti.z;
  int g1 = offsets[ti.y] + ti.w;
  int i = threadIdx.x;  // 128 threads, H/4 = 128 float4 per row
  float4 a = Y[(size_t)g0 * (HD / 4) + i];
  float4 b = Y[(size_t)g1 * (HD / 4) + i];
  out[(size_t)t * (HD / 4) + i] = make_float4(a.x + b.x, a.y + b.y, a.z + b.z, a.w + b.w);
}

extern "C" void kernel_launch(void* const* d_in, const int* in_sizes, int n_in,
                              void* d_out, int out_size, void* d_ws, size_t ws_size,
                              hipStream_t stream) {
  const float* x    = (const float*)d_in[0];
  const float* rw   = (const float*)d_in[1];
  const float* fc1w = (const float*)d_in[2];
  const float* fc1b = (const float*)d_in[3];
  const float* fc2w = (const float*)d_in[4];
  const float* fc2b = (const float*)d_in[5];

  float* out   = (float*)d_out;
  float* probs = out + (size_t)T_TOKENS * HD;
  float* topk  = probs + (size_t)T_TOKENS * NE;

  char* p = (char*)d_ws;
  auto carve = [&](size_t bytes) { char* r = p; p += (bytes + 255) & ~(size_t)255; return r; };
  int*    counts     = (int*)carve(NE * CSTRIDE * sizeof(int));
  int*    offsets    = (int*)carve(NE * sizeof(int));
  int*    bucket_tok = (int*)carve((size_t)NE * CAP * sizeof(int));
  float*  bucket_w   = (float*)carve((size_t)NE * CAP * sizeof(float));
  int4*   tok_info   = (int4*)carve((size_t)T_TOKENS * sizeof(int4));
  ushort* xb   = (ushort*)carve((size_t)T_TOKENS * HD * 2);
  ushort* w1b  = (ushort*)carve((size_t)NE * FD * HD * 2);
  ushort* w2b  = (ushort*)carve((size_t)NE * HD * FD * 2);
  ushort* Abuf = (ushort*)carve((size_t)T_TOKENS * 2 * FD * 2);  // compact GELU out, bf16
  float*  Y    = (float*)carve((size_t)T_TOKENS * 2 * HD * 4);   // gated FC2 rows, fp32

  hipMemsetAsync(counts, 0, NE * CSTRIDE * sizeof(int), stream);
  cvt_bf16<<<2048, 256, 0, stream>>>((const float4*)x, (ushort4*)xb, T_TOKENS * HD / 4);
  cvt_bf16<<<2048, 256, 0, stream>>>((const float4*)fc1w, (ushort4*)w1b, NE * FD * HD / 4);
  cvt_bf16<<<2048, 256, 0, stream>>>((const float4*)fc2w, (ushort4*)w2b, NE * HD * FD / 4);
  router_kernel<<<T_TOKENS / 64, 256, 0, stream>>>(x, rw, probs, topk, counts, bucket_tok,
                                                   bucket_w, tok_info);
  scan_kernel<<<1, 64, 0, stream>>>(counts, offsets);
  ffn_gemm<true><<<dim3(FD / BN, CAP / BM, NE), 256, 0, stream>>>(
      xb, w1b, fc1b, counts, offsets, bucket_tok, bucket_w, Abuf, nullptr, HD, FD);
  ffn_gemm<false><<<dim3(HD / BN, CAP / BM, NE), 256, 0, stream>>>(
      Abuf, w2b, fc2b, counts, offsets, bucket_tok, bucket_w, nullptr, Y, FD, HD);
  combine_kernel<<<T_TOKENS, 128, 0, stream>>>((const float4*)Y, tok_info, offsets, (float4*)out);
}

// Round 3
// 339.092 us; speedup vs baseline: 1.5569x; 1.1106x over previous
//
#include <hip/hip_runtime.h>

// Problem constants: B=4, S=2048 -> T=8192 tokens; H=512, F=2048, E=8, K=2.
#define T_TOKENS 8192
#define HD 512
#define FD 2048
#define NE 8
#define CAP 8192   // per-expert bucket capacity (worst case all tokens -> one expert)
#define CSTRIDE 32 // counter padding: 32 ints = 128B, one counter per cache line

#define BM 128
#define BN 128
#define BK 32

typedef __attribute__((ext_vector_type(8))) short short8;   // 8 bf16 = 4 VGPRs
typedef __attribute__((ext_vector_type(4))) float f32x4;    // MFMA accumulator

__device__ __forceinline__ ushort f2bf(float f) {
  union { float f; unsigned u; } v; v.f = f;
  unsigned u = v.u;
  return (ushort)((u + 0x7fffu + ((u >> 16) & 1u)) >> 16);  // RNE
}

// async global->LDS, 16B per lane. LDS dest is wave-uniform base + lane*16,
// satisfied because our chunk index == tid maps linearly into LDS.
__device__ __forceinline__ void gld16(const void* g, void* l) {
  __builtin_amdgcn_global_load_lds(
      (const __attribute__((address_space(1))) void*)g,
      (__attribute__((address_space(3))) void*)l, 16, 0, 0);
}

// ---------------- fp32 -> bf16 bulk convert ----------------
__global__ void cvt_bf16(const float4* __restrict__ src, ushort4* __restrict__ dst, int n4) {
  int i = blockIdx.x * blockDim.x + threadIdx.x;
  int st = gridDim.x * blockDim.x;
  for (; i < n4; i += st) {
    float4 v = src[i];
    ushort4 o;
    o.x = f2bf(v.x); o.y = f2bf(v.y); o.z = f2bf(v.z); o.w = f2bf(v.w);
    dst[i] = o;
  }
}

// ---------------- router: logits -> softmax -> top2 -> buckets ----------------
// Hierarchical slot assignment (R1 fix: flat atomics on one line = 193 us).
#define TPW 16
__global__ void router_kernel(const float* __restrict__ x, const float* __restrict__ rw,
                              float* __restrict__ probs_out, float* __restrict__ topk_out,
                              int* __restrict__ counts, int* __restrict__ bucket_tok,
                              float* __restrict__ bucket_w, int4* __restrict__ tok_info) {
  __shared__ int lcnt[NE];
  __shared__ int lbase[NE];
  __shared__ int ls_e0[64], ls_e1[64], ls_s0[64], ls_s1[64];
  __shared__ float ls_w0[64], ls_w1[64];

  int wave = threadIdx.x >> 6, lane = threadIdx.x & 63;
  if (threadIdx.x < NE) lcnt[threadIdx.x] = 0;
  __syncthreads();

  int tbase = blockIdx.x * 64;
  for (int it = 0; it < TPW; it++) {
    int lt = wave * TPW + it;
    int t = tbase + lt;
    float acc[NE];
#pragma unroll
    for (int e = 0; e < NE; e++) acc[e] = 0.f;
    const float* xr = x + (size_t)t * HD;
    for (int c = 0; c < HD; c += 64) {
      float xv = xr[c + lane];
#pragma unroll
      for (int e = 0; e < NE; e++) acc[e] += xv * rw[e * HD + c + lane];
    }
#pragma unroll
    for (int e = 0; e < NE; e++) {
#pragma unroll
      for (int s = 32; s > 0; s >>= 1) acc[e] += __shfl_xor(acc[e], s, 64);
    }
    if (lane == 0) {
      float m = acc[0];
#pragma unroll
      for (int e = 1; e < NE; e++) m = fmaxf(m, acc[e]);
      float p[NE], s = 0.f;
#pragma unroll
      for (int e = 0; e < NE; e++) { p[e] = expf(acc[e] - m); s += p[e]; }
      float inv = 1.f / s;
#pragma unroll
      for (int e = 0; e < NE; e++) { p[e] *= inv; probs_out[(size_t)t * NE + e] = p[e]; }
      int i0 = 0;
#pragma unroll
      for (int e = 1; e < NE; e++) if (p[e] > p[i0]) i0 = e;
      int i1 = (i0 == 0) ? 1 : 0;
#pragma unroll
      for (int e = 0; e < NE; e++) if (e != i0 && p[e] > p[i1]) i1 = e;
      float r = 1.f / (p[i0] + p[i1] + 1e-9f);
      topk_out[(size_t)t * 2 + 0] = (float)i0;
      topk_out[(size_t)t * 2 + 1] = (float)i1;
      ls_e0[lt] = i0; ls_e1[lt] = i1;
      ls_w0[lt] = p[i0] * r; ls_w1[lt] = p[i1] * r;
      ls_s0[lt] = atomicAdd(&lcnt[i0], 1);
      ls_s1[lt] = atomicAdd(&lcnt[i1], 1);
    }
  }
  __syncthreads();
  if (threadIdx.x < NE)
    lbase[threadIdx.x] = atomicAdd(&counts[threadIdx.x * CSTRIDE], lcnt[threadIdx.x]);
  __syncthreads();
  if (threadIdx.x < 64) {
    int lt = threadIdx.x, t = tbase + lt;
    int e0 = ls_e0[lt], e1 = ls_e1[lt];
    int g0 = lbase[e0] + ls_s0[lt];
    int g1 = lbase[e1] + ls_s1[lt];
    bucket_tok[e0 * CAP + g0] = t; bucket_w[e0 * CAP + g0] = ls_w0[lt];
    bucket_tok[e1 * CAP + g1] = t; bucket_w[e1 * CAP + g1] = ls_w1[lt];
    tok_info[t] = make_int4(e0, e1, g0, g1);
  }
}

__global__ void scan_kernel(const int* __restrict__ counts, int* __restrict__ offsets) {
  if (threadIdx.x == 0) {
    int o = 0;
#pragma unroll
    for (int e = 0; e < NE; e++) { offsets[e] = o; o += counts[e * CSTRIDE]; }
  }
}

// ---------------- grouped GEMM (bf16 MFMA 16x16x32), FC1 and FC2 ----------------
// m97-style: global_load_lds width=16 staging, unpadded linear LDS tiles.
// Epilogue round-trips through LDS for 16B contiguous global stores.
template <bool IS_FC1>
__global__ __launch_bounds__(256, 2)
void ffn_gemm(const ushort* __restrict__ Ab, const ushort* __restrict__ Bw,
              const float* __restrict__ bias, const int* __restrict__ counts,
              const int* __restrict__ offsets, const int* __restrict__ bucket_tok,
              const float* __restrict__ bucket_w, ushort* __restrict__ Aout,
              float* __restrict__ Yout, int KD, int ND) {
  int e = blockIdx.z;
  int cnt = counts[e * CSTRIDE];
  int m0 = blockIdx.y * BM;
  if (m0 >= cnt) return;
  int n0 = blockIdx.x * BN;
  int off = offsets[e];

  __shared__ alignas(16) ushort smem[10240];  // 20 KB: 16 KB staging, reused by epilogue
  ushort* As = smem;             // [BM][BK] linear, 4096 ushorts
  ushort* Bs = smem + BM * BK;   // [BN][BK] linear

  int tid = threadIdx.x;
  int wid = tid >> 6, lid = tid & 63;
  int wm = wid >> 1, wn = wid & 1;
  int q = lid >> 4, l16 = lid & 15;

  // staging: chunk index == tid (and tid+256); row = tid>>2, kseg = (tid&3)*8
  int crow = tid >> 2;
  int cseg = (tid & 3) * 8;

  int mr0 = min(m0 + crow, cnt - 1);
  int mr1 = min(m0 + crow + 64, cnt - 1);
  const ushort *a0, *a1;
  if (IS_FC1) {
    a0 = Ab + (size_t)bucket_tok[e * CAP + mr0] * KD + cseg;
    a1 = Ab + (size_t)bucket_tok[e * CAP + mr1] * KD + cseg;
  } else {
    a0 = Ab + (size_t)(off + mr0) * KD + cseg;
    a1 = Ab + (size_t)(off + mr1) * KD + cseg;
  }
  const ushort* b0 = Bw + ((size_t)e * ND + n0 + crow) * KD + cseg;
  const ushort* b1 = b0 + (size_t)64 * KD;
  ushort* lA0 = As + tid * 8;
  ushort* lA1 = As + (tid + 256) * 8;
  ushort* lB0 = Bs + tid * 8;
  ushort* lB1 = Bs + (tid + 256) * 8;

  f32x4 acc[4][4] = {};

  for (int k0 = 0; k0 < KD; k0 += BK) {
    gld16(a0 + k0, lA0);
    gld16(a1 + k0, lA1);
    gld16(b0 + k0, lB0);
    gld16(b1 + k0, lB1);
    __syncthreads();  // compiler inserts s_waitcnt vmcnt(0) before s_barrier
    short8 af[4], bfr[4];
#pragma unroll
    for (int i = 0; i < 4; i++)
      af[i] = *(const short8*)&As[(wm * 64 + i * 16 + l16) * BK + q * 8];
#pragma unroll
    for (int j = 0; j < 4; j++)
      bfr[j] = *(const short8*)&Bs[(wn * 64 + j * 16 + l16) * BK + q * 8];
#pragma unroll
    for (int i = 0; i < 4; i++)
#pragma unroll
      for (int j = 0; j < 4; j++)
        acc[i][j] = __builtin_amdgcn_mfma_f32_16x16x32_bf16(af[i], bfr[j], acc[i][j], 0, 0, 0);
    __syncthreads();
  }

  // ---- epilogue through LDS: per i-round, stage 32 rows x 128 cols, then
  // read back 16B chunks and store 256B-contiguous row segments. ----
  float bcol[4];
#pragma unroll
  for (int j = 0; j < 4; j++)
    bcol[j] = bias[(size_t)e * ND + n0 + wn * 64 + j * 16 + l16];

  if (IS_FC1) {
    ushort* Ct = smem;  // [32][136] bf16 (pad 8 breaks q-conflict; row base 272B, 16B-aligned)
#pragma unroll
    for (int i = 0; i < 4; i++) {
      __syncthreads();
#pragma unroll
      for (int j = 0; j < 4; j++)
#pragma unroll
        for (int r = 0; r < 4; r++) {
          float v = acc[i][j][r] + bcol[j];
          float g = 0.5f * v * (1.0f + erff(v * 0.70710678118654752f));
          Ct[(wm * 16 + q * 4 + r) * 136 + wn * 64 + j * 16 + l16] = f2bf(g);
        }
      __syncthreads();
#pragma unroll
      for (int u = 0; u < 2; u++) {
        int c = tid + u * 256;            // 512 chunks of 8 bf16
        int ml = c >> 4, cc = c & 15;
        int gm = m0 + (ml >> 4) * 64 + i * 16 + (ml & 15);
        if (gm < cnt)
          *(uint4*)&Aout[(size_t)(off + gm) * ND + n0 + cc * 8] =
              *(const uint4*)&Ct[ml * 136 + cc * 8];
      }
    }
  } else {
    float* Ct = (float*)smem;  // [32][132] fp32 (16896 B <= 20480; row base 528B, 16B-aligned)
#pragma unroll
    for (int i = 0; i < 4; i++) {
      __syncthreads();
#pragma unroll
      for (int r = 0; r < 4; r++) {
        int gm = m0 + wm * 64 + i * 16 + q * 4 + r;
        float wgt = bucket_w[e * CAP + min(gm, cnt - 1)];
#pragma unroll
        for (int j = 0; j < 4; j++)
          Ct[(wm * 16 + q * 4 + r) * 132 + wn * 64 + j * 16 + l16] = wgt * (acc[i][j][r] + bcol[j]);
      }
      __syncthreads();
#pragma unroll
      for (int u = 0; u < 4; u++) {
        int c = tid + u * 256;            // 1024 chunks of 4 floats
        int ml = c >> 5, cc = c & 31;
        int gm = m0 + (ml >> 4) * 64 + i * 16 + (ml & 15);
        if (gm < cnt)
          *(float4*)&Yout[(size_t)(off + gm) * ND + n0 + cc * 4] =
              *(const float4*)&Ct[ml * 132 + cc * 4];
      }
    }
  }
}

// ---------------- combine: out[t] = Y[row(e0,s0)] + Y[row(e1,s1)] ----------------
__global__ void combine_kernel(const float4* __restrict__ Y, const int4* __restrict__ tok_info,
                               const int* __restrict__ offsets, float4* __restrict__ out) {
  int t = blockIdx.x;
  int4 ti = tok_info[t];
  int g0 = offsets[ti.x] + ti.z;
  int g1 = offsets[ti.y] + ti.w;
  int i = threadIdx.x;  // 128 threads, H/4 = 128 float4 per row
  float4 a = Y[(size_t)g0 * (HD / 4) + i];
  float4 b = Y[(size_t)g1 * (HD / 4) + i];
  out[(size_t)t * (HD / 4) + i] = make_float4(a.x + b.x, a.y + b.y, a.z + b.z, a.w + b.w);
}

extern "C" void kernel_launch(void* const* d_in, const int* in_sizes, int n_in,
                              void* d_out, int out_size, void* d_ws, size_t ws_size,
                              hipStream_t stream) {
  const float* x    = (const float*)d_in[0];
  const float* rw   = (const float*)d_in[1];
  const float* fc1w = (const float*)d_in[2];
  const float* fc1b = (const float*)d_in[3];
  const float* fc2w = (const float*)d_in[4];
  const float* fc2b = (const float*)d_in[5];

  float* out   = (float*)d_out;
  float* probs = out + (size_t)T_TOKENS * HD;
  float* topk  = probs + (size_t)T_TOKENS * NE;

  char* p = (char*)d_ws;
  auto carve = [&](size_t bytes) { char* r = p; p += (bytes + 255) & ~(size_t)255; return r; };
  int*    counts     = (int*)carve(NE * CSTRIDE * sizeof(int));
  int*    offsets    = (int*)carve(NE * sizeof(int));
  int*    bucket_tok = (int*)carve((size_t)NE * CAP * sizeof(int));
  float*  bucket_w   = (float*)carve((size_t)NE * CAP * sizeof(float));
  int4*   tok_info   = (int4*)carve((size_t)T_TOKENS * sizeof(int4));
  ushort* xb   = (ushort*)carve((size_t)T_TOKENS * HD * 2);
  ushort* w1b  = (ushort*)carve((size_t)NE * FD * HD * 2);
  ushort* w2b  = (ushort*)carve((size_t)NE * HD * FD * 2);
  ushort* Abuf = (ushort*)carve((size_t)T_TOKENS * 2 * FD * 2);  // compact GELU out, bf16
  float*  Y    = (float*)carve((size_t)T_TOKENS * 2 * HD * 4);   // gated FC2 rows, fp32

  hipMemsetAsync(counts, 0, NE * CSTRIDE * sizeof(int), stream);
  cvt_bf16<<<2048, 256, 0, stream>>>((const float4*)x, (ushort4*)xb, T_TOKENS * HD / 4);
  cvt_bf16<<<2048, 256, 0, stream>>>((const float4*)fc1w, (ushort4*)w1b, NE * FD * HD / 4);
  cvt_bf16<<<2048, 256, 0, stream>>>((const float4*)fc2w, (ushort4*)w2b, NE * HD * FD / 4);
  router_kernel<<<T_TOKENS / 64, 256, 0, stream>>>(x, rw, probs, topk, counts, bucket_tok,
                                                   bucket_w, tok_info);
  scan_kernel<<<1, 64, 0, stream>>>(counts, offsets);
  ffn_gemm<true><<<dim3(FD / BN, CAP / BM, NE), 256, 0, stream>>>(
      xb, w1b, fc1b, counts, offsets, bucket_tok, bucket_w, Abuf, nullptr, HD, FD);
  ffn_gemm<false><<<dim3(HD / BN, CAP / BM, NE), 256, 0, stream>>>(
      Abuf, w2b, fc2b, counts, offsets, bucket_tok, bucket_w, nullptr, Y, FD, HD);
  combine_kernel<<<T_TOKENS, 128, 0, stream>>>((const float4*)Y, tok_info, offsets, (float4*)out);
}